// Round 5
// baseline (137.073 us; speedup 1.0000x reference)
//
#include <hip/hip_runtime.h>
#include <stdint.h>

// MaskedMHSA: B=2 T=2048 E=768 H=12 DH=64
#define NROWS 4096      // B*T
#define EMB   768
#define NQKV  2304      // 3*E
#define TSEQ  2048
#define NHEAD 12
#define NBH   24        // B*H

typedef unsigned short u16;
typedef u16  ushort4v __attribute__((ext_vector_type(4)));
typedef u16  ushort8 __attribute__((ext_vector_type(8)));
typedef __bf16 bf16x8 __attribute__((ext_vector_type(8)));
typedef float f32x4 __attribute__((ext_vector_type(4)));

typedef const __attribute__((address_space(1))) void* gas_ptr;
typedef __attribute__((address_space(3))) void* las_ptr;

__device__ __forceinline__ u16 f2bf(float f) {
  union { float f; uint32_t u; } v; v.f = f;
  uint32_t u = v.u;
  return (u16)((u + 0x7fffu + ((u >> 16) & 1u)) >> 16);
}
__device__ __forceinline__ float bf2f(u16 u) {
  union { uint32_t u; float f; } v; v.u = ((uint32_t)u) << 16;
  return v.f;
}
__device__ __forceinline__ uint32_t cvtpk(float lo, float hi) {
  uint32_t r;
  asm("v_cvt_pk_bf16_f32 %0, %1, %2" : "=v"(r) : "v"(lo), "v"(hi));
  return r;
}

#define VMCNT0 asm volatile("s_waitcnt vmcnt(0)" ::: "memory")
#define LGKM0  asm volatile("s_waitcnt lgkmcnt(0)" ::: "memory")
#define SBAR   __builtin_amdgcn_s_barrier()
#define SCHED0 __builtin_amdgcn_sched_barrier(0)

// ---------------- init: zero the 8 per-XCD task counters ----------------
__global__ void k_zero(uint32_t* cnt) {
  if (threadIdx.x < 8) cnt[threadIdx.x] = 0;
}

// ---------------- pack kernels ----------------
__global__ __launch_bounds__(256) void k_pack_x(const float* __restrict__ x, u16* __restrict__ xb) {
  int i = (blockIdx.x * 256 + threadIdx.x) * 8;
  float4 a = *(const float4*)(x + i);
  float4 b = *(const float4*)(x + i + 4);
  uint4 o;
  o.x = cvtpk(a.x, a.y); o.y = cvtpk(a.z, a.w);
  o.z = cvtpk(b.x, b.y); o.w = cvtpk(b.z, b.w);
  *(uint4*)(xb + i) = o;
}

__global__ __launch_bounds__(256) void k_pack_wqkv(const float* __restrict__ Wq, const float* __restrict__ Wk,
                            const float* __restrict__ Wv, const float* __restrict__ bq,
                            const float* __restrict__ bk, const float* __restrict__ bv,
                            u16* __restrict__ wt, float* __restrict__ bias) {
  int idx = blockIdx.x * 256 + threadIdx.x;
  if (idx >= NQKV * EMB) return;
  int n = idx / EMB, e = idx - n * EMB;
  int sel = n / EMB;
  int c = n - sel * EMB;
  int h = c >> 6, d = c & 63;
  const float* W = sel == 0 ? Wq : (sel == 1 ? Wk : Wv);
  wt[idx] = f2bf(W[((size_t)h * EMB + e) * 64 + d]);
  if (e == 0) {
    const float* bs = sel == 0 ? bq : (sel == 1 ? bk : bv);
    bias[n] = bs[h * 64 + d];
  }
}

__global__ __launch_bounds__(256) void k_pack_wo(const float* __restrict__ Wo, u16* __restrict__ wot) {
  int idx = blockIdx.x * 256 + threadIdx.x;
  if (idx >= EMB * EMB) return;
  int n = idx / EMB, e = idx - n * EMB;
  wot[idx] = f2bf(Wo[(size_t)e * EMB + n]);
}

// ---------------- GEMM: C[M,N] = A[M,K] * Bt[N,K]^T + bias ----------------
// BK=64, XOR-swizzled LDS (stage via pre-swizzled global col), 2x2 waves.
// OUT_MODE: 0 = bf16 out, 1 = f32 out, 2 = bf16 qkv + V-region transposed to vt[d][t]
template<int BM, int BN, int OUT_MODE>
__global__ __launch_bounds__(256) void k_gemm(const u16* __restrict__ A, const u16* __restrict__ Bt,
                                              const float* __restrict__ bias, void* __restrict__ Cout,
                                              u16* __restrict__ vtout, int M, int N, int K) {
  constexpr int MR = BM / 32, NR = BN / 32;
  __shared__ u16 lds_a[BM * 64];
  __shared__ u16 lds_b[BN * 64];
  int tid = threadIdx.x;
  int w = tid >> 6, lane = tid & 63;
  int wr = w >> 1, wc = w & 1;
  int m0 = blockIdx.x * BM, n0 = blockIdx.y * BN;
  int lrow = lane & 15, g = lane >> 4;

  f32x4 zero = {0.f, 0.f, 0.f, 0.f};
  f32x4 acc[MR][NR];
  for (int m = 0; m < MR; ++m) for (int n = 0; n < NR; ++n) acc[m][n] = zero;

  int l8 = lane >> 3, c8 = lane & 7;

  for (int k0 = 0; k0 < K; k0 += 64) {
#pragma unroll
    for (int i = 0; i < BM / 32; ++i) {
      int row = w * (BM / 4) + 8 * i + l8;
      int c16 = c8 ^ (row & 7);
      const u16* ga = A + (size_t)(m0 + row) * K + k0 + c16 * 8;
      __builtin_amdgcn_global_load_lds((gas_ptr)ga, (las_ptr)(lds_a + (w * (BM / 4) + 8 * i) * 64), 16, 0, 0);
    }
#pragma unroll
    for (int i = 0; i < BN / 32; ++i) {
      int row = w * (BN / 4) + 8 * i + l8;
      int c16 = c8 ^ (row & 7);
      const u16* gb = Bt + (size_t)(n0 + row) * K + k0 + c16 * 8;
      __builtin_amdgcn_global_load_lds((gas_ptr)gb, (las_ptr)(lds_b + (w * (BN / 4) + 8 * i) * 64), 16, 0, 0);
    }
    __syncthreads();
    bf16x8 af[MR][2], bfr[NR][2];
#pragma unroll
    for (int m = 0; m < MR; ++m)
#pragma unroll
      for (int kc = 0; kc < 2; ++kc) {
        int row = wr * (BM / 2) + m * 16 + lrow;
        int ch = (kc * 4 + g) ^ (row & 7);
        af[m][kc] = *(const bf16x8*)(lds_a + row * 64 + ch * 8);
      }
#pragma unroll
    for (int n = 0; n < NR; ++n)
#pragma unroll
      for (int kc = 0; kc < 2; ++kc) {
        int row = wc * (BN / 2) + n * 16 + lrow;
        int ch = (kc * 4 + g) ^ (row & 7);
        bfr[n][kc] = *(const bf16x8*)(lds_b + row * 64 + ch * 8);
      }
#pragma unroll
    for (int kc = 0; kc < 2; ++kc)
#pragma unroll
      for (int m = 0; m < MR; ++m)
#pragma unroll
        for (int n = 0; n < NR; ++n)
          acc[m][n] = __builtin_amdgcn_mfma_f32_16x16x32_bf16(af[m][kc], bfr[n][kc], acc[m][n], 0, 0, 0);
    __syncthreads();
  }

#pragma unroll
  for (int m = 0; m < MR; ++m)
#pragma unroll
    for (int n = 0; n < NR; ++n) {
      int col = n0 + wc * (BN / 2) + n * 16 + lrow;
      float bcol = bias[col];
      int row0 = m0 + wr * (BM / 2) + m * 16 + 4 * g;
      if (OUT_MODE == 2 && col >= 2 * EMB) {
        // V region -> vt[(y*64+d)][t], t = row0..row0+3 contiguous
        int c = col - 2 * EMB;
        int hh = c >> 6, d = c & 63;
        int bb = row0 >> 11, t = row0 & 2047;
        int y = bb * NHEAD + hh;
        ushort4v pk;
#pragma unroll
        for (int r = 0; r < 4; ++r) pk[r] = f2bf(acc[m][n][r] + bcol);
        *(ushort4v*)(vtout + (size_t)(y * 64 + d) * TSEQ + t) = pk;
      } else {
#pragma unroll
        for (int r = 0; r < 4; ++r) {
          int row = row0 + r;
          float v = acc[m][n][r] + bcol;
          if (OUT_MODE == 1) ((float*)Cout)[(size_t)row * N + col] = v;
          else               ((u16*)Cout)[(size_t)row * N + col] = f2bf(v);
        }
      }
    }
}

// ---------------- causal flash attention: persistent + per-XCD queues + split-K ----------------
// Fixed-max softmax makes chunk partials summable: task = (y, qb, chunk).
// qb<16: single chunk [0,qb] -> writes aout directly.
// qb>=16: chunk0 = tiles [0,16) (16 tiles), chunk1 = tiles [16,qb] (<=16 tiles)
//         -> write bf16 partial O + f32 partial l; k_combine merges.
// 144 tasks per XCD, pulled in descending-length order.
__global__ __launch_bounds__(256, 4) void k_attn(const u16* __restrict__ qkv, const u16* __restrict__ vt,
                                                 u16* __restrict__ aout, uint32_t* __restrict__ cnt,
                                                 u16* __restrict__ pO, float* __restrict__ pL) {
  __shared__ u16 kbuf[2][64 * 64];
  __shared__ u16 vbuf[2][64 * 64];
  __shared__ u16 pbuf[4][16 * 64];
  __shared__ int task_s;
  int tid = threadIdx.x;
  int w = tid >> 6, lane = tid & 63;
  int ql = lane & 15, g = lane >> 4;
  int xcd = blockIdx.x & 7;
  const float sc2 = 0.18033688f;  // (1/8) * log2(e)
  u16* pw = &pbuf[w][0];
  int swz = (ql & 7) << 3;
  int l8 = lane >> 3, c8 = lane & 7;

  for (;;) {
    if (tid == 0) task_s = (int)atomicAdd(&cnt[xcd], 1u);
    __syncthreads();
    int tau = task_s;
    __syncthreads();
    if (tau >= 144) break;

    // decode task (descending length order)
    int rank = tau / 3, yl = tau - rank * 3;
    int qb, t0, t1ex, cslot; bool direct;
    if (rank < 16)       { qb = 16 + rank; t0 = 0;  t1ex = 16;     cslot = 0; direct = false; }
    else if (!(rank & 1)){ int i = (rank - 16) >> 1; qb = 31 - i; t0 = 16; t1ex = qb + 1; cslot = 1; direct = false; }
    else                 { int i = (rank - 16) >> 1; qb = 15 - i; t0 = 0;  t1ex = qb + 1; cslot = 0; direct = true; }

    int y = xcd * 3 + yl;
    int b = y / NHEAD, h = y - b * NHEAD;
    int qrow0w = qb * 64 + w * 16;
    int qg = qrow0w + ql;

    // Q fragments (B-operand: col=lane&15=q, k=8g+j)
    const u16* qp = qkv + (size_t)(b * TSEQ + qg) * NQKV + h * 64;
    bf16x8 bq0 = *(const bf16x8*)(qp + g * 8);
    bf16x8 bq1 = *(const bf16x8*)(qp + 32 + g * 8);

    const u16* kst = qkv + (size_t)(b * TSEQ) * NQKV + EMB + h * 64;
    const u16* vst = vt + (size_t)y * 64 * TSEQ;

    f32x4 zero = {0.f, 0.f, 0.f, 0.f};
    f32x4 o[4]; for (int n = 0; n < 4; ++n) o[n] = zero;
    float lr = 0.f;

    auto STAGE = [&](int bi, int t_) {
#pragma unroll
      for (int i = 0; i < 2; ++i) {
        int row = i * 32 + 8 * w + l8;
        int c16 = c8 ^ (row & 7);
        const u16* gk = kst + (size_t)(t_ * 64 + row) * NQKV + c16 * 8;
        __builtin_amdgcn_global_load_lds((gas_ptr)gk, (las_ptr)(&kbuf[bi][(i * 32 + 8 * w) * 64]), 16, 0, 0);
        const u16* gv = vst + (size_t)row * TSEQ + t_ * 64 + c16 * 8;
        __builtin_amdgcn_global_load_lds((gas_ptr)gv, (las_ptr)(&vbuf[bi][(i * 32 + 8 * w) * 64]), 16, 0, 0);
      }
    };

    STAGE(t0 & 1, t0);
    for (int t = t0; t < t1ex; ++t) {
      int cur = t & 1;
      VMCNT0;
      SBAR;
      if (t + 1 < t1ex) STAGE(cur ^ 1, t + 1);

      const u16* kb = &kbuf[cur][0];
      const u16* vb = &vbuf[cur][0];
      int s0 = t * 64;

      // QK^T swapped: lane holds S^T[s = s0+sblk*16+4g+r][q = qg]
      f32x4 st[4];
#pragma unroll
      for (int sblk = 0; sblk < 4; ++sblk) {
        int row = sblk * 16 + ql;
        bf16x8 ka0 = *(const bf16x8*)(kb + ((row * 64 + 8 * g) ^ swz));
        bf16x8 ka1 = *(const bf16x8*)(kb + ((row * 64 + 32 + 8 * g) ^ swz));
        f32x4 acc = zero;
        acc = __builtin_amdgcn_mfma_f32_16x16x32_bf16(ka0, bq0, acc, 0, 0, 0);
        acc = __builtin_amdgcn_mfma_f32_16x16x32_bf16(ka1, bq1, acc, 0, 0, 0);
        st[sblk] = acc;
      }

      // fixed-max softmax: e = exp2(S*sc2 - 2.0); mask only when t == qb
      bool lastt = (t == qb);
      float e[4][4];
#pragma unroll
      for (int sblk = 0; sblk < 4; ++sblk)
#pragma unroll
        for (int r = 0; r < 4; ++r) {
          float vv = __builtin_fmaf(st[sblk][r], sc2, -2.0f);
          if (lastt) {
            int sg = s0 + sblk * 16 + 4 * g + r;
            if (sg > qg) vv = -1e30f;
          }
          float ee = __builtin_amdgcn_exp2f(vv);
          e[sblk][r] = ee;
          lr += ee;
        }

      // P^T -> per-wave LDS [q][s] (swizzled), read back as PV A-fragments
#pragma unroll
      for (int sblk = 0; sblk < 4; ++sblk) {
        uint2 dw;
        dw.x = cvtpk(e[sblk][0], e[sblk][1]);
        dw.y = cvtpk(e[sblk][2], e[sblk][3]);
        *(uint2*)(pw + ((ql * 64 + sblk * 16 + 4 * g) ^ swz)) = dw;
      }
      LGKM0; SCHED0;
      bf16x8 ap0 = *(const bf16x8*)(pw + ((ql * 64 + 8 * g) ^ swz));
      bf16x8 ap1 = *(const bf16x8*)(pw + ((ql * 64 + 32 + 8 * g) ^ swz));

      // PV: O[q][d] += P[q][s] * Vt[d][s]
#pragma unroll
      for (int n = 0; n < 4; ++n) {
        int row = n * 16 + ql;
        bf16x8 vb0 = *(const bf16x8*)(vb + ((row * 64 + 8 * g) ^ swz));
        bf16x8 vb1 = *(const bf16x8*)(vb + ((row * 64 + 32 + 8 * g) ^ swz));
        o[n] = __builtin_amdgcn_mfma_f32_16x16x32_bf16(ap0, vb0, o[n], 0, 0, 0);
        o[n] = __builtin_amdgcn_mfma_f32_16x16x32_bf16(ap1, vb1, o[n], 0, 0, 0);
      }
    }

    // l reduce: lane partial -> full row sum for q-row ql (replicated over g)
    float lw = lr;
    lw += __shfl_xor(lw, 16);
    lw += __shfl_xor(lw, 32);

    if (direct) {
      float linv = 1.0f / lw;
      float li[4];
#pragma unroll
      for (int r = 0; r < 4; ++r) li[r] = __shfl(linv, 4 * g + r);
#pragma unroll
      for (int n = 0; n < 4; ++n)
#pragma unroll
        for (int r = 0; r < 4; ++r) {
          int q = qrow0w + 4 * g + r;
          aout[(size_t)(b * TSEQ + q) * EMB + h * 64 + n * 16 + ql] = f2bf(o[n][r] * li[r]);
        }
    } else {
      int blk = y * 16 + (qb - 16);
      u16* po = pO + ((size_t)blk * 2 + cslot) * 4096;
      float* pl = pL + ((size_t)blk * 2 + cslot) * 64;
      if (g == 0) pl[w * 16 + ql] = lw;
#pragma unroll
      for (int n = 0; n < 4; ++n)
#pragma unroll
        for (int r = 0; r < 4; ++r) {
          int qloc = w * 16 + 4 * g + r;
          po[qloc * 64 + n * 16 + ql] = f2bf(o[n][r]);
        }
    }
  }
}

// ---------------- combine split-K partials ----------------
__global__ __launch_bounds__(256) void k_combine(const u16* __restrict__ pO, const float* __restrict__ pL,
                                                 u16* __restrict__ aout) {
  int blk = blockIdx.x;           // y*16 + (qb-16)
  int y = blk >> 4, qb = 16 + (blk & 15);
  int b = y / NHEAD, h = y - b * NHEAD;
  int tid = threadIdx.x;
  int row = tid >> 2, c0 = (tid & 3) * 16;
  const u16* p0 = pO + ((size_t)blk * 2) * 4096 + row * 64 + c0;
  const u16* p1 = p0 + 4096;
  float l = pL[blk * 128 + row] + pL[blk * 128 + 64 + row];
  float rinv = 1.0f / l;
  ushort8 a0 = *(const ushort8*)(p0);
  ushort8 a1 = *(const ushort8*)(p0 + 8);
  ushort8 b0 = *(const ushort8*)(p1);
  ushort8 b1 = *(const ushort8*)(p1 + 8);
  ushort8 o0, o1;
#pragma unroll
  for (int j = 0; j < 8; j += 2) {
    uint32_t w0 = cvtpk((bf2f(a0[j]) + bf2f(b0[j])) * rinv, (bf2f(a0[j+1]) + bf2f(b0[j+1])) * rinv);
    o0[j] = (u16)(w0 & 0xffff); o0[j+1] = (u16)(w0 >> 16);
    uint32_t w1 = cvtpk((bf2f(a1[j]) + bf2f(b1[j])) * rinv, (bf2f(a1[j+1]) + bf2f(b1[j+1])) * rinv);
    o1[j] = (u16)(w1 & 0xffff); o1[j+1] = (u16)(w1 >> 16);
  }
  u16* dst = aout + (size_t)(b * TSEQ + qb * 64 + row) * EMB + h * 64 + c0;
  *(ushort8*)dst = o0;
  *(ushort8*)(dst + 8) = o1;
}

// ---------------- LayerNorm + residual ----------------
__global__ __launch_bounds__(256) void k_ln_res(const float* __restrict__ proj, const float* __restrict__ x,
                                                const float* __restrict__ gamma, const float* __restrict__ beta,
                                                float* __restrict__ out) {
  __shared__ float smem[2][4];
  int row = blockIdx.x;
  const float* pr = proj + (size_t)row * EMB;
  const float* xr = x + (size_t)row * EMB;
  float* orow = out + (size_t)row * EMB;
  int tid = threadIdx.x;
  float v[3];
  float s = 0.f, s2 = 0.f;
#pragma unroll
  for (int i = 0; i < 3; ++i) { v[i] = pr[tid + 256 * i]; s += v[i]; s2 += v[i] * v[i]; }
#pragma unroll
  for (int m = 1; m < 64; m <<= 1) { s += __shfl_xor(s, m); s2 += __shfl_xor(s2, m); }
  int w = tid >> 6, lane = tid & 63;
  if (lane == 0) { smem[0][w] = s; smem[1][w] = s2; }
  __syncthreads();
  s  = smem[0][0] + smem[0][1] + smem[0][2] + smem[0][3];
  s2 = smem[1][0] + smem[1][1] + smem[1][2] + smem[1][3];
  float mu = s * (1.f / EMB);
  float var = s2 * (1.f / EMB) - mu * mu;
  float rstd = rsqrtf(var + 1e-5f);
#pragma unroll
  for (int i = 0; i < 3; ++i) {
    int c = tid + 256 * i;
    orow[c] = xr[c] + (v[i] - mu) * rstd * gamma[c] + beta[c];
  }
}

// ---------------- launch ----------------
extern "C" void kernel_launch(void* const* d_in, const int* in_sizes, int n_in,
                              void* d_out, int out_size, void* d_ws, size_t ws_size,
                              hipStream_t stream) {
  const float* x     = (const float*)d_in[0];
  const float* Wq    = (const float*)d_in[1];
  const float* bq    = (const float*)d_in[2];
  const float* Wk    = (const float*)d_in[3];
  const float* bk    = (const float*)d_in[4];
  const float* Wv    = (const float*)d_in[5];
  const float* bv    = (const float*)d_in[6];
  const float* Wo    = (const float*)d_in[7];
  const float* bo    = (const float*)d_in[8];
  const float* gamma = (const float*)d_in[9];
  const float* beta  = (const float*)d_in[10];
  float* out = (float*)d_out;

  char* ws = (char*)d_ws;
  size_t off = 0;
  u16* xb    = (u16*)(ws + off); off += (size_t)NROWS * EMB * 2;
  u16* wqkvt = (u16*)(ws + off); off += (size_t)NQKV * EMB * 2;
  u16* wot   = (u16*)(ws + off); off += (size_t)EMB * EMB * 2;
  float* bqkv = (float*)(ws + off); off += (size_t)NQKV * 4;
  uint32_t* cnt = (uint32_t*)(ws + off); off += 64;
  u16* qkv   = (u16*)(ws + off); off += (size_t)NROWS * NQKV * 2;
  u16* vt    = (u16*)(ws + off); off += (size_t)NBH * 64 * TSEQ * 2;
  u16* aout  = (u16*)(ws + off); off += (size_t)NROWS * EMB * 2;
  u16* pO    = (u16*)(ws + off); off += (size_t)NBH * 16 * 2 * 4096 * 2;  // 6.29 MB
  float* pL  = (float*)(ws + off); off += (size_t)NBH * 16 * 2 * 64 * 4;  // 196 KB
  float* proj = (float*)qkv;  // alias: qkv dead after attention

  k_zero<<<1, 64, 0, stream>>>(cnt);
  k_pack_x<<<NROWS * EMB / (256 * 8), 256, 0, stream>>>(x, xb);
  k_pack_wqkv<<<(NQKV * EMB + 255) / 256, 256, 0, stream>>>(Wq, Wk, Wv, bq, bk, bv, wqkvt, bqkv);
  k_pack_wo<<<(EMB * EMB + 255) / 256, 256, 0, stream>>>(Wo, wot);
  k_gemm<128, 128, 2><<<dim3(NROWS / 128, NQKV / 128), 256, 0, stream>>>(xb, wqkvt, bqkv, qkv, vt, NROWS, NQKV, EMB);
  k_attn<<<dim3(1024), 256, 0, stream>>>(qkv, vt, aout, cnt, pO, pL);
  k_combine<<<dim3(NBH * 16), 256, 0, stream>>>(pO, pL, aout);
  k_gemm<128, 64, 1><<<dim3(NROWS / 128, EMB / 64), 256, 0, stream>>>(aout, wot, bo, proj, nullptr, NROWS, EMB, EMB);
  k_ln_res<<<NROWS, 256, 0, stream>>>(proj, x, gamma, beta, out);
}

// Round 6
// 114.491 us; speedup vs baseline: 1.1972x; 1.1972x over previous
//
#include <hip/hip_runtime.h>
#include <stdint.h>

// MaskedMHSA: B=2 T=2048 E=768 H=12 DH=64
#define NROWS 4096      // B*T
#define EMB   768
#define NQKV  2304      // 3*E
#define TSEQ  2048
#define NHEAD 12
#define NBH   24        // B*H

typedef unsigned short u16;
typedef u16  ushort4v __attribute__((ext_vector_type(4)));
typedef u16  ushort8 __attribute__((ext_vector_type(8)));
typedef __bf16 bf16x8 __attribute__((ext_vector_type(8)));
typedef float f32x4 __attribute__((ext_vector_type(4)));

typedef const __attribute__((address_space(1))) void* gas_ptr;
typedef __attribute__((address_space(3))) void* las_ptr;

__device__ __forceinline__ u16 f2bf(float f) {
  union { float f; uint32_t u; } v; v.f = f;
  uint32_t u = v.u;
  return (u16)((u + 0x7fffu + ((u >> 16) & 1u)) >> 16);
}
__device__ __forceinline__ float bf2f(u16 u) {
  union { uint32_t u; float f; } v; v.u = ((uint32_t)u) << 16;
  return v.f;
}
__device__ __forceinline__ uint32_t cvtpk(float lo, float hi) {
  uint32_t r;
  asm("v_cvt_pk_bf16_f32 %0, %1, %2" : "=v"(r) : "v"(lo), "v"(hi));
  return r;
}

#define VMCNT0 asm volatile("s_waitcnt vmcnt(0)" ::: "memory")
#define LGKM0  asm volatile("s_waitcnt lgkmcnt(0)" ::: "memory")
#define SBAR   __builtin_amdgcn_s_barrier()
#define SCHED0 __builtin_amdgcn_sched_barrier(0)

// ---------------- unified pack kernel ----------------
// blocks [0,1536):   x f32 -> bf16
// blocks [1536,1968): Wq/Wk/Wv [h][e][d] -> wt[n=sel*768+h*64+d][e]  (LDS transpose)
// blocks [1968,2112): Wo [e][n] -> wot[n][e]                         (LDS transpose)
// block 0 thread<8: zero per-XCD task counters
__global__ __launch_bounds__(256) void k_pack(const float* __restrict__ x, u16* __restrict__ xb,
                                              const float* __restrict__ Wq, const float* __restrict__ Wk,
                                              const float* __restrict__ Wv, u16* __restrict__ wt,
                                              const float* __restrict__ Wo, u16* __restrict__ wot,
                                              uint32_t* __restrict__ cnt) {
  int bid = blockIdx.x, tid = threadIdx.x;
  if (bid == 0 && tid < 8) cnt[tid] = 0;
  if (bid < 1536) {
    int i = bid * 2048 + tid * 8;
    float4 a = *(const float4*)(x + i);
    float4 b = *(const float4*)(x + i + 4);
    uint4 o;
    o.x = cvtpk(a.x, a.y); o.y = cvtpk(a.z, a.w);
    o.z = cvtpk(b.x, b.y); o.w = cvtpk(b.z, b.w);
    *(uint4*)(xb + i) = o;
    return;
  }
  __shared__ u16 lds[64][68];
  if (bid < 1968) {
    int t = bid - 1536;
    int sel = t / 144, rest = t - sel * 144;
    int h = rest / 12, ec = rest - h * 12;          // e-chunk of 64
    const float* W = sel == 0 ? Wq : (sel == 1 ? Wk : Wv);
    const float* src = W + ((size_t)(h * EMB + ec * 64) * 64);
    int e = tid >> 2, d0 = (tid & 3) * 16;
#pragma unroll
    for (int j = 0; j < 4; ++j) {
      float4 v = *(const float4*)(src + (size_t)e * 64 + d0 + 4 * j);
      ushort4v pk;
      uint32_t w0 = cvtpk(v.x, v.y), w1 = cvtpk(v.z, v.w);
      pk[0] = (u16)(w0 & 0xffff); pk[1] = (u16)(w0 >> 16);
      pk[2] = (u16)(w1 & 0xffff); pk[3] = (u16)(w1 >> 16);
      *(ushort4v*)(&lds[e][d0 + 4 * j]) = pk;
    }
    __syncthreads();
    int d = tid >> 2, e0 = (tid & 3) * 16;
    ushort8 o0, o1;
#pragma unroll
    for (int j = 0; j < 8; ++j) { o0[j] = lds[e0 + j][d]; o1[j] = lds[e0 + 8 + j][d]; }
    int n = sel * EMB + h * 64 + d;
    u16* dst = wt + (size_t)n * EMB + ec * 64 + e0;
    *(ushort8*)dst = o0;
    *(ushort8*)(dst + 8) = o1;
  } else {
    int t = bid - 1968;
    int er = t / 12, nc = t - er * 12;              // e-row-chunk, n-chunk (64 each)
    int e = tid >> 2, n0 = (tid & 3) * 16;
#pragma unroll
    for (int j = 0; j < 4; ++j) {
      float4 v = *(const float4*)(Wo + (size_t)(er * 64 + e) * EMB + nc * 64 + n0 + 4 * j);
      ushort4v pk;
      uint32_t w0 = cvtpk(v.x, v.y), w1 = cvtpk(v.z, v.w);
      pk[0] = (u16)(w0 & 0xffff); pk[1] = (u16)(w0 >> 16);
      pk[2] = (u16)(w1 & 0xffff); pk[3] = (u16)(w1 >> 16);
      *(ushort4v*)(&lds[e][n0 + 4 * j]) = pk;
    }
    __syncthreads();
    int n = tid >> 2, e0 = (tid & 3) * 16;
    ushort8 o0, o1;
#pragma unroll
    for (int j = 0; j < 8; ++j) { o0[j] = lds[e0 + j][n]; o1[j] = lds[e0 + 8 + j][n]; }
    u16* dst = wot + (size_t)(nc * 64 + n) * EMB + er * 64 + e0;
    *(ushort8*)dst = o0;
    *(ushort8*)(dst + 8) = o1;
  }
}

// ---------------- GEMM: C[M,N] = A[M,K] * Bt[N,K]^T + bias ----------------
// BK=64, XOR-swizzled LDS (stage via pre-swizzled global col), 2x2 waves.
// OUT_MODE: 1 = f32 out (bias=b0[col]), 2 = bf16 qkv out with per-sel bias
//           (b0/b1/b2 = bq/bk/bv) + V-region transposed to vt[d][t]
template<int BM, int BN, int OUT_MODE>
__global__ __launch_bounds__(256) void k_gemm(const u16* __restrict__ A, const u16* __restrict__ Bt,
                                              const float* __restrict__ b0, const float* __restrict__ b1,
                                              const float* __restrict__ b2, void* __restrict__ Cout,
                                              u16* __restrict__ vtout, int M, int N, int K) {
  constexpr int MR = BM / 32, NR = BN / 32;
  __shared__ u16 lds_a[BM * 64];
  __shared__ u16 lds_b[BN * 64];
  int tid = threadIdx.x;
  int w = tid >> 6, lane = tid & 63;
  int wr = w >> 1, wc = w & 1;
  int m0 = blockIdx.x * BM, n0 = blockIdx.y * BN;
  int lrow = lane & 15, g = lane >> 4;

  f32x4 zero = {0.f, 0.f, 0.f, 0.f};
  f32x4 acc[MR][NR];
  for (int m = 0; m < MR; ++m) for (int n = 0; n < NR; ++n) acc[m][n] = zero;

  int l8 = lane >> 3, c8 = lane & 7;

  for (int k0 = 0; k0 < K; k0 += 64) {
#pragma unroll
    for (int i = 0; i < BM / 32; ++i) {
      int row = w * (BM / 4) + 8 * i + l8;
      int c16 = c8 ^ (row & 7);
      const u16* ga = A + (size_t)(m0 + row) * K + k0 + c16 * 8;
      __builtin_amdgcn_global_load_lds((gas_ptr)ga, (las_ptr)(lds_a + (w * (BM / 4) + 8 * i) * 64), 16, 0, 0);
    }
#pragma unroll
    for (int i = 0; i < BN / 32; ++i) {
      int row = w * (BN / 4) + 8 * i + l8;
      int c16 = c8 ^ (row & 7);
      const u16* gb = Bt + (size_t)(n0 + row) * K + k0 + c16 * 8;
      __builtin_amdgcn_global_load_lds((gas_ptr)gb, (las_ptr)(lds_b + (w * (BN / 4) + 8 * i) * 64), 16, 0, 0);
    }
    __syncthreads();
    bf16x8 af[MR][2], bfr[NR][2];
#pragma unroll
    for (int m = 0; m < MR; ++m)
#pragma unroll
      for (int kc = 0; kc < 2; ++kc) {
        int row = wr * (BM / 2) + m * 16 + lrow;
        int ch = (kc * 4 + g) ^ (row & 7);
        af[m][kc] = *(const bf16x8*)(lds_a + row * 64 + ch * 8);
      }
#pragma unroll
    for (int n = 0; n < NR; ++n)
#pragma unroll
      for (int kc = 0; kc < 2; ++kc) {
        int row = wc * (BN / 2) + n * 16 + lrow;
        int ch = (kc * 4 + g) ^ (row & 7);
        bfr[n][kc] = *(const bf16x8*)(lds_b + row * 64 + ch * 8);
      }
#pragma unroll
    for (int kc = 0; kc < 2; ++kc)
#pragma unroll
      for (int m = 0; m < MR; ++m)
#pragma unroll
        for (int n = 0; n < NR; ++n)
          acc[m][n] = __builtin_amdgcn_mfma_f32_16x16x32_bf16(af[m][kc], bfr[n][kc], acc[m][n], 0, 0, 0);
    __syncthreads();
  }

#pragma unroll
  for (int m = 0; m < MR; ++m)
#pragma unroll
    for (int n = 0; n < NR; ++n) {
      int col = n0 + wc * (BN / 2) + n * 16 + lrow;
      float bcol;
      if (OUT_MODE == 1) bcol = b0[col];
      else {
        int sel = col >= 1536 ? 2 : (col >= 768 ? 1 : 0);
        const float* bs = sel == 0 ? b0 : (sel == 1 ? b1 : b2);
        bcol = bs[col - sel * EMB];
      }
      int row0 = m0 + wr * (BM / 2) + m * 16 + 4 * g;
      if (OUT_MODE == 2 && col >= 2 * EMB) {
        // V region -> vt[(y*64+d)][t], t = row0..row0+3 contiguous
        int c = col - 2 * EMB;
        int hh = c >> 6, d = c & 63;
        int bb = row0 >> 11, t = row0 & 2047;
        int y = bb * NHEAD + hh;
        ushort4v pk;
#pragma unroll
        for (int r = 0; r < 4; ++r) pk[r] = f2bf(acc[m][n][r] + bcol);
        *(ushort4v*)(vtout + (size_t)(y * 64 + d) * TSEQ + t) = pk;
      } else {
#pragma unroll
        for (int r = 0; r < 4; ++r) {
          int row = row0 + r;
          float v = acc[m][n][r] + bcol;
          if (OUT_MODE == 1) ((float*)Cout)[(size_t)row * N + col] = v;
          else               ((u16*)Cout)[(size_t)row * N + col] = f2bf(v);
        }
      }
    }
}

// ---------------- causal flash attention: persistent (768 = 3/CU) + per-XCD queues + split-K ----------------
// Fixed-max softmax makes chunk partials summable: task = (y, qb, chunk).
// qb<16: single chunk -> aout direct. qb>=16: chunk0 = [0,16), chunk1 = [16,qb]
// -> bf16 partial O + f32 partial l; k_combine merges. 144 tasks/XCD, longest first.
__global__ __launch_bounds__(256, 3) void k_attn(const u16* __restrict__ qkv, const u16* __restrict__ vt,
                                                 u16* __restrict__ aout, uint32_t* __restrict__ cnt,
                                                 u16* __restrict__ pO, float* __restrict__ pL) {
  __shared__ u16 kbuf[2][64 * 64];
  __shared__ u16 vbuf[2][64 * 64];
  __shared__ u16 pbuf[4][16 * 64];
  __shared__ int task_s;
  int tid = threadIdx.x;
  int w = tid >> 6, lane = tid & 63;
  int ql = lane & 15, g = lane >> 4;
  int xcd = blockIdx.x & 7;
  const float sc2 = 0.18033688f;  // (1/8) * log2(e)
  u16* pw = &pbuf[w][0];
  int swz = (ql & 7) << 3;
  int l8 = lane >> 3, c8 = lane & 7;

  for (;;) {
    if (tid == 0) task_s = (int)atomicAdd(&cnt[xcd], 1u);
    __syncthreads();
    int tau = task_s;
    __syncthreads();
    if (tau >= 144) break;

    // decode task (descending length order)
    int rank = tau / 3, yl = tau - rank * 3;
    int qb, t0, t1ex, cslot; bool direct;
    if (rank < 16)       { qb = 16 + rank; t0 = 0;  t1ex = 16;     cslot = 0; direct = false; }
    else if (!(rank & 1)){ int i = (rank - 16) >> 1; qb = 31 - i; t0 = 16; t1ex = qb + 1; cslot = 1; direct = false; }
    else                 { int i = (rank - 16) >> 1; qb = 15 - i; t0 = 0;  t1ex = qb + 1; cslot = 0; direct = true; }

    int y = xcd * 3 + yl;
    int b = y / NHEAD, h = y - b * NHEAD;
    int qrow0w = qb * 64 + w * 16;
    int qg = qrow0w + ql;

    // Q fragments (B-operand: col=lane&15=q, k=8g+j)
    const u16* qp = qkv + (size_t)(b * TSEQ + qg) * NQKV + h * 64;
    bf16x8 bq0 = *(const bf16x8*)(qp + g * 8);
    bf16x8 bq1 = *(const bf16x8*)(qp + 32 + g * 8);

    const u16* kst = qkv + (size_t)(b * TSEQ) * NQKV + EMB + h * 64;
    const u16* vst = vt + (size_t)y * 64 * TSEQ;

    f32x4 zero = {0.f, 0.f, 0.f, 0.f};
    f32x4 o[4]; for (int n = 0; n < 4; ++n) o[n] = zero;
    float lr = 0.f;

    auto STAGE = [&](int bi, int t_) {
#pragma unroll
      for (int i = 0; i < 2; ++i) {
        int row = i * 32 + 8 * w + l8;
        int c16 = c8 ^ (row & 7);
        const u16* gk = kst + (size_t)(t_ * 64 + row) * NQKV + c16 * 8;
        __builtin_amdgcn_global_load_lds((gas_ptr)gk, (las_ptr)(&kbuf[bi][(i * 32 + 8 * w) * 64]), 16, 0, 0);
        const u16* gv = vst + (size_t)row * TSEQ + t_ * 64 + c16 * 8;
        __builtin_amdgcn_global_load_lds((gas_ptr)gv, (las_ptr)(&vbuf[bi][(i * 32 + 8 * w) * 64]), 16, 0, 0);
      }
    };

    STAGE(t0 & 1, t0);
    for (int t = t0; t < t1ex; ++t) {
      int cur = t & 1;
      VMCNT0;
      SBAR;
      if (t + 1 < t1ex) STAGE(cur ^ 1, t + 1);

      const u16* kb = &kbuf[cur][0];
      const u16* vb = &vbuf[cur][0];
      int s0 = t * 64;

      // QK^T swapped: lane holds S^T[s = s0+sblk*16+4g+r][q = qg]
      f32x4 st[4];
#pragma unroll
      for (int sblk = 0; sblk < 4; ++sblk) {
        int row = sblk * 16 + ql;
        bf16x8 ka0 = *(const bf16x8*)(kb + ((row * 64 + 8 * g) ^ swz));
        bf16x8 ka1 = *(const bf16x8*)(kb + ((row * 64 + 32 + 8 * g) ^ swz));
        f32x4 acc = zero;
        acc = __builtin_amdgcn_mfma_f32_16x16x32_bf16(ka0, bq0, acc, 0, 0, 0);
        acc = __builtin_amdgcn_mfma_f32_16x16x32_bf16(ka1, bq1, acc, 0, 0, 0);
        st[sblk] = acc;
      }

      // fixed-max softmax: e = exp2(S*sc2 - 2.0); mask only when t == qb
      bool lastt = (t == qb);
      float e[4][4];
#pragma unroll
      for (int sblk = 0; sblk < 4; ++sblk)
#pragma unroll
        for (int r = 0; r < 4; ++r) {
          float vv = __builtin_fmaf(st[sblk][r], sc2, -2.0f);
          if (lastt) {
            int sg = s0 + sblk * 16 + 4 * g + r;
            if (sg > qg) vv = -1e30f;
          }
          float ee = __builtin_amdgcn_exp2f(vv);
          e[sblk][r] = ee;
          lr += ee;
        }

      // P^T -> per-wave LDS [q][s] (swizzled), read back as PV A-fragments
#pragma unroll
      for (int sblk = 0; sblk < 4; ++sblk) {
        uint2 dw;
        dw.x = cvtpk(e[sblk][0], e[sblk][1]);
        dw.y = cvtpk(e[sblk][2], e[sblk][3]);
        *(uint2*)(pw + ((ql * 64 + sblk * 16 + 4 * g) ^ swz)) = dw;
      }
      LGKM0; SCHED0;
      bf16x8 ap0 = *(const bf16x8*)(pw + ((ql * 64 + 8 * g) ^ swz));
      bf16x8 ap1 = *(const bf16x8*)(pw + ((ql * 64 + 32 + 8 * g) ^ swz));

      // PV: O[q][d] += P[q][s] * Vt[d][s]
#pragma unroll
      for (int n = 0; n < 4; ++n) {
        int row = n * 16 + ql;
        bf16x8 vb0 = *(const bf16x8*)(vb + ((row * 64 + 8 * g) ^ swz));
        bf16x8 vb1 = *(const bf16x8*)(vb + ((row * 64 + 32 + 8 * g) ^ swz));
        o[n] = __builtin_amdgcn_mfma_f32_16x16x32_bf16(ap0, vb0, o[n], 0, 0, 0);
        o[n] = __builtin_amdgcn_mfma_f32_16x16x32_bf16(ap1, vb1, o[n], 0, 0, 0);
      }
    }

    // l reduce: lane partial -> full row sum for q-row ql (replicated over g)
    float lw = lr;
    lw += __shfl_xor(lw, 16);
    lw += __shfl_xor(lw, 32);

    if (direct) {
      float linv = 1.0f / lw;
      float li[4];
#pragma unroll
      for (int r = 0; r < 4; ++r) li[r] = __shfl(linv, 4 * g + r);
#pragma unroll
      for (int n = 0; n < 4; ++n)
#pragma unroll
        for (int r = 0; r < 4; ++r) {
          int q = qrow0w + 4 * g + r;
          aout[(size_t)(b * TSEQ + q) * EMB + h * 64 + n * 16 + ql] = f2bf(o[n][r] * li[r]);
        }
    } else {
      int blk = y * 16 + (qb - 16);
      u16* po = pO + ((size_t)blk * 2 + cslot) * 4096;
      float* pl = pL + ((size_t)blk * 2 + cslot) * 64;
      if (g == 0) pl[w * 16 + ql] = lw;
#pragma unroll
      for (int n = 0; n < 4; ++n)
#pragma unroll
        for (int r = 0; r < 4; ++r) {
          int qloc = w * 16 + 4 * g + r;
          po[qloc * 64 + n * 16 + ql] = f2bf(o[n][r]);
        }
    }
  }
}

// ---------------- combine split-K partials ----------------
__global__ __launch_bounds__(256) void k_combine(const u16* __restrict__ pO, const float* __restrict__ pL,
                                                 u16* __restrict__ aout) {
  int blk = blockIdx.x;           // y*16 + (qb-16)
  int y = blk >> 4, qb = 16 + (blk & 15);
  int b = y / NHEAD, h = y - b * NHEAD;
  int tid = threadIdx.x;
  int row = tid >> 2, c0 = (tid & 3) * 16;
  const u16* p0 = pO + ((size_t)blk * 2) * 4096 + row * 64 + c0;
  const u16* p1 = p0 + 4096;
  float l = pL[blk * 128 + row] + pL[blk * 128 + 64 + row];
  float rinv = 1.0f / l;
  ushort8 a0 = *(const ushort8*)(p0);
  ushort8 a1 = *(const ushort8*)(p0 + 8);
  ushort8 b0 = *(const ushort8*)(p1);
  ushort8 b1 = *(const ushort8*)(p1 + 8);
  ushort8 o0, o1;
#pragma unroll
  for (int j = 0; j < 8; j += 2) {
    uint32_t w0 = cvtpk((bf2f(a0[j]) + bf2f(b0[j])) * rinv, (bf2f(a0[j+1]) + bf2f(b0[j+1])) * rinv);
    o0[j] = (u16)(w0 & 0xffff); o0[j+1] = (u16)(w0 >> 16);
    uint32_t w1 = cvtpk((bf2f(a1[j]) + bf2f(b1[j])) * rinv, (bf2f(a1[j+1]) + bf2f(b1[j+1])) * rinv);
    o1[j] = (u16)(w1 & 0xffff); o1[j+1] = (u16)(w1 >> 16);
  }
  u16* dst = aout + (size_t)(b * TSEQ + qb * 64 + row) * EMB + h * 64 + c0;
  *(ushort8*)dst = o0;
  *(ushort8*)(dst + 8) = o1;
}

// ---------------- LayerNorm + residual ----------------
__global__ __launch_bounds__(256) void k_ln_res(const float* __restrict__ proj, const float* __restrict__ x,
                                                const float* __restrict__ gamma, const float* __restrict__ beta,
                                                float* __restrict__ out) {
  __shared__ float smem[2][4];
  int row = blockIdx.x;
  const float* pr = proj + (size_t)row * EMB;
  const float* xr = x + (size_t)row * EMB;
  float* orow = out + (size_t)row * EMB;
  int tid = threadIdx.x;
  float v[3];
  float s = 0.f, s2 = 0.f;
#pragma unroll
  for (int i = 0; i < 3; ++i) { v[i] = pr[tid + 256 * i]; s += v[i]; s2 += v[i] * v[i]; }
#pragma unroll
  for (int m = 1; m < 64; m <<= 1) { s += __shfl_xor(s, m); s2 += __shfl_xor(s2, m); }
  int w = tid >> 6, lane = tid & 63;
  if (lane == 0) { smem[0][w] = s; smem[1][w] = s2; }
  __syncthreads();
  s  = smem[0][0] + smem[0][1] + smem[0][2] + smem[0][3];
  s2 = smem[1][0] + smem[1][1] + smem[1][2] + smem[1][3];
  float mu = s * (1.f / EMB);
  float var = s2 * (1.f / EMB) - mu * mu;
  float rstd = rsqrtf(var + 1e-5f);
#pragma unroll
  for (int i = 0; i < 3; ++i) {
    int c = tid + 256 * i;
    orow[c] = xr[c] + (v[i] - mu) * rstd * gamma[c] + beta[c];
  }
}

// ---------------- launch ----------------
extern "C" void kernel_launch(void* const* d_in, const int* in_sizes, int n_in,
                              void* d_out, int out_size, void* d_ws, size_t ws_size,
                              hipStream_t stream) {
  const float* x     = (const float*)d_in[0];
  const float* Wq    = (const float*)d_in[1];
  const float* bq    = (const float*)d_in[2];
  const float* Wk    = (const float*)d_in[3];
  const float* bk    = (const float*)d_in[4];
  const float* Wv    = (const float*)d_in[5];
  const float* bv    = (const float*)d_in[6];
  const float* Wo    = (const float*)d_in[7];
  const float* bo    = (const float*)d_in[8];
  const float* gamma = (const float*)d_in[9];
  const float* beta  = (const float*)d_in[10];
  float* out = (float*)d_out;

  char* ws = (char*)d_ws;
  size_t off = 0;
  u16* xb    = (u16*)(ws + off); off += (size_t)NROWS * EMB * 2;
  u16* wqkvt = (u16*)(ws + off); off += (size_t)NQKV * EMB * 2;
  u16* wot   = (u16*)(ws + off); off += (size_t)EMB * EMB * 2;
  uint32_t* cnt = (uint32_t*)(ws + off); off += 64;
  u16* qkv   = (u16*)(ws + off); off += (size_t)NROWS * NQKV * 2;
  u16* vt    = (u16*)(ws + off); off += (size_t)NBH * 64 * TSEQ * 2;
  u16* aout  = (u16*)(ws + off); off += (size_t)NROWS * EMB * 2;
  u16* pO    = (u16*)(ws + off); off += (size_t)NBH * 16 * 2 * 4096 * 2;  // 6.29 MB
  float* pL  = (float*)(ws + off); off += (size_t)NBH * 16 * 2 * 64 * 4;  // 196 KB
  float* proj = (float*)qkv;  // alias: qkv dead after attention

  k_pack<<<dim3(2112), 256, 0, stream>>>(x, xb, Wq, Wk, Wv, wqkvt, Wo, wot, cnt);
  k_gemm<128, 128, 2><<<dim3(NROWS / 128, NQKV / 128), 256, 0, stream>>>(xb, wqkvt, bq, bk, bv, qkv, vt, NROWS, NQKV, EMB);
  k_attn<<<dim3(768), 256, 0, stream>>>(qkv, vt, aout, cnt, pO, pL);
  k_combine<<<dim3(NBH * 16), 256, 0, stream>>>(pO, pL, aout);
  k_gemm<128, 64, 1><<<dim3(NROWS / 128, EMB / 64), 256, 0, stream>>>(aout, wot, bo, nullptr, nullptr, proj, nullptr, NROWS, EMB, EMB);
  k_ln_res<<<NROWS, 256, 0, stream>>>(proj, x, gamma, beta, out);
}